// Round 1
// 247.143 us; speedup vs baseline: 1.1824x; 1.1824x over previous
//
#include <hip/hip_runtime.h>
#include <stdint.h>

#define F_DIM 128
#define H_DIM 64
#define K_DIM 16
#define BUK_SH 8
#define NCH 256

typedef _Float16 half2v __attribute__((ext_vector_type(2)));
typedef _Float16 half4 __attribute__((ext_vector_type(4)));
typedef _Float16 f16x8 __attribute__((ext_vector_type(8)));
typedef float f32x4 __attribute__((ext_vector_type(4)));

// ---- radix-partition CSR build (5 kernels) -----------------------------
__global__ __launch_bounds__(256) void k_hist(const int* __restrict__ dst,
                                              int* __restrict__ hist,
                                              int E, int CH, int NBUK) {
    __shared__ int h[512];
    int t = threadIdx.x, c = blockIdx.x;
    for (int i = t; i < NBUK; i += 256) h[i] = 0;
    __syncthreads();
    int s = c * CH, e = min(s + CH, E);
    for (int i = s + t; i < e; i += 256) atomicAdd(&h[dst[i] >> BUK_SH], 1);
    __syncthreads();
    for (int i = t; i < NBUK; i += 256) hist[i * NCH + c] = h[i];
}

__global__ __launch_bounds__(256) void k_scanBkt(int* __restrict__ hist,
                                                 int* __restrict__ bktTot) {
    __shared__ int sh[256];
    int b = blockIdx.x, t = threadIdx.x;
    int v = hist[b * NCH + t];
    sh[t] = v;
    __syncthreads();
    for (int off = 1; off < 256; off <<= 1) {
        int x = (t >= off) ? sh[t - off] : 0;
        __syncthreads();
        sh[t] += x;
        __syncthreads();
    }
    hist[b * NCH + t] = sh[t] - v;
    if (t == 255) bktTot[b] = sh[255];
}

__global__ __launch_bounds__(256) void k_scanTot(const int* __restrict__ bktTot,
                                                 int* __restrict__ bktBase, int NBUK) {
    __shared__ int sh[256];
    int t = threadIdx.x;
    int i0 = 2 * t, i1 = 2 * t + 1;
    int v0 = (i0 < NBUK) ? bktTot[i0] : 0;
    int v1 = (i1 < NBUK) ? bktTot[i1] : 0;
    int s = v0 + v1;
    sh[t] = s;
    __syncthreads();
    for (int off = 1; off < 256; off <<= 1) {
        int x = (t >= off) ? sh[t - off] : 0;
        __syncthreads();
        sh[t] += x;
        __syncthreads();
    }
    int excl = sh[t] - s;
    if (i0 < NBUK) bktBase[i0] = excl;
    if (i1 < NBUK) bktBase[i1] = excl + v0;
    if (t == 255) bktBase[NBUK] = sh[255];
}

__global__ __launch_bounds__(256) void k_scatter(const int* __restrict__ src,
                                                 const int* __restrict__ dst,
                                                 const int* __restrict__ hist,
                                                 const int* __restrict__ bktBase,
                                                 uint32_t* __restrict__ binned,
                                                 int E, int CH, int NBUK) {
    __shared__ int ctr[512];
    int t = threadIdx.x, c = blockIdx.x;
    for (int i = t; i < NBUK; i += 256) ctr[i] = bktBase[i] + hist[i * NCH + c];
    __syncthreads();
    int s = c * CH, e = min(s + CH, E);
    for (int i = s + t; i < e; i += 256) {
        int d = dst[i];
        int pos = atomicAdd(&ctr[d >> BUK_SH], 1);
        binned[pos] = (uint32_t)src[i] | ((uint32_t)(d & 255) << 20);
    }
}

__global__ __launch_bounds__(256) void k_fine2(const uint32_t* __restrict__ binned,
                                               const int* __restrict__ bktBase,
                                               int* __restrict__ rowptr,
                                               int* __restrict__ col, int N) {
    __shared__ int h[256], sc[256], slotL[256];
    int b = blockIdx.x, t = threadIdx.x;
    int n0 = b << BUK_SH;
    int s = bktBase[b], e = bktBase[b + 1];
    h[t] = 0;
    __syncthreads();
    for (int i = s + t; i < e; i += 256) atomicAdd(&h[binned[i] >> 20], 1);
    __syncthreads();
    int v = h[t];
    sc[t] = v;
    __syncthreads();
    for (int off = 1; off < 256; off <<= 1) {
        int x = (t >= off) ? sc[t - off] : 0;
        __syncthreads();
        sc[t] += x;
        __syncthreads();
    }
    int excl = sc[t] - v;
    int n = n0 + t;
    int rowbase = s + n0;
    if (n < N) {
        int rp = rowbase + excl + t;
        rowptr[n] = rp;
        col[rp] = n;
        slotL[t] = rp + 1;
        if (n == N - 1) rowptr[N] = rp + v + 1;
    }
    __syncthreads();
    for (int i = s + t; i < e; i += 256) {
        uint32_t p = binned[i];
        int pos = atomicAdd(&slotL[p >> 20], 1);
        col[pos] = (int)(p & 0xFFFFFu);
    }
}

// ---- Layer 1 GEMM via MFMA (inline W swizzle fp32->fp16) ---------------
__global__ __launch_bounds__(256) void k_gemm1m(
        const float* __restrict__ X,
        const float* __restrict__ W1l, const float* __restrict__ W1r,
        _Float16* __restrict__ xlh, _Float16* __restrict__ xrh, int N) {
    __shared__ _Float16 Ws[16384];
    __shared__ _Float16 Xs[128 * 136];
    int t = threadIdx.x;
    int n0 = blockIdx.x * 128;
    int validRows = N - n0; if (validRows > 128) validRows = 128;
    for (int i = t; i < 4096; i += 256) {
        int k = i >> 5, c4 = (i & 31) << 2;
        float4 v = (c4 < 64) ? *(const float4*)&W1l[k * 64 + c4]
                             : *(const float4*)&W1r[k * 64 + (c4 - 64)];
        int s = k >> 5, q = (k >> 3) & 3, j = k & 7;
        float vv[4] = {v.x, v.y, v.z, v.w};
#pragma unroll
        for (int u = 0; u < 4; ++u) {
            int C = c4 + u, c = C >> 4, n = C & 15;
            Ws[(((c * 4 + s) * 4 + q) * 16 + n) * 8 + j] = (_Float16)vv[u];
        }
    }
    for (int i = t; i < 4096; i += 256) {
        int r = i >> 5, c4 = (i & 31) << 2;
        float4 v = {0.f, 0.f, 0.f, 0.f};
        if (r < validRows) v = *(const float4*)&X[(long)(n0 + r) * 128 + c4];
        half4 hv;
        hv.x = (_Float16)v.x; hv.y = (_Float16)v.y;
        hv.z = (_Float16)v.z; hv.w = (_Float16)v.w;
        *(half4*)&Xs[r * 136 + c4] = hv;
    }
    __syncthreads();
    int w = t >> 6, lane = t & 63;
    int m = lane & 15, q = lane >> 4;
    f32x4 acc[2][8];
#pragma unroll
    for (int a = 0; a < 2; ++a)
#pragma unroll
        for (int c = 0; c < 8; ++c) acc[a][c] = (f32x4){0.f, 0.f, 0.f, 0.f};
#pragma unroll
    for (int s = 0; s < 4; ++s) {
        f16x8 a0 = *(const f16x8*)&Xs[(w * 32 + m) * 136 + s * 32 + q * 8];
        f16x8 a1 = *(const f16x8*)&Xs[(w * 32 + 16 + m) * 136 + s * 32 + q * 8];
#pragma unroll
        for (int c = 0; c < 8; ++c) {
            f16x8 b = *(const f16x8*)&Ws[(((c * 4 + s) * 4 + q) * 16 + m) * 8];
            acc[0][c] = __builtin_amdgcn_mfma_f32_16x16x32_f16(a0, b, acc[0][c], 0, 0, 0);
            acc[1][c] = __builtin_amdgcn_mfma_f32_16x16x32_f16(a1, b, acc[1][c], 0, 0, 0);
        }
    }
#pragma unroll
    for (int sub = 0; sub < 2; ++sub)
#pragma unroll
    for (int c = 0; c < 8; ++c)
#pragma unroll
    for (int r = 0; r < 4; ++r) {
        int gn = n0 + w * 32 + sub * 16 + q * 4 + r;
        if (gn < N) {
            int C = c * 16 + m;
            _Float16 v = (_Float16)acc[sub][c][r];
            if (C < 64) xlh[(long)gn * 64 + C] = v;
            else        xrh[(long)gn * 64 + (C - 64)] = v;
        }
    }
}

// ---- Layer 2 GEMM via MFMA (fp16 H input, inline W swizzle) ------------
__global__ __launch_bounds__(256) void k_gemm2m(
        const _Float16* __restrict__ Hm,
        const float* __restrict__ W2l, const float* __restrict__ W2r,
        _Float16* __restrict__ xlh, _Float16* __restrict__ xrh, int N) {
    __shared__ _Float16 Ws2[2048];
    __shared__ _Float16 Hs[256 * 72];
    int t = threadIdx.x;
    int n0 = blockIdx.x * 256;
    int validRows = N - n0; if (validRows > 256) validRows = 256;
    for (int i = t; i < 512; i += 256) {
        int k = i >> 3, c4 = (i & 7) << 2;
        float4 v = (c4 < 16) ? *(const float4*)&W2l[k * 16 + c4]
                             : *(const float4*)&W2r[k * 16 + (c4 - 16)];
        int s = k >> 5, q = (k >> 3) & 3, j = k & 7;
        float vv[4] = {v.x, v.y, v.z, v.w};
#pragma unroll
        for (int u = 0; u < 4; ++u) {
            int C = c4 + u, c = C >> 4, n = C & 15;
            Ws2[(((c * 2 + s) * 4 + q) * 16 + n) * 8 + j] = (_Float16)vv[u];
        }
    }
    for (int i = t; i < 2048; i += 256) {
        int r = i >> 3, c8 = (i & 7) << 3;
        f16x8 v = {0, 0, 0, 0, 0, 0, 0, 0};
        if (r < validRows) v = *(const f16x8*)&Hm[(long)(n0 + r) * 64 + c8];
        *(f16x8*)&Hs[r * 72 + c8] = v;
    }
    __syncthreads();
    int w = t >> 6, lane = t & 63;
    int m = lane & 15, q = lane >> 4;
    f32x4 acc[4][2];
#pragma unroll
    for (int a = 0; a < 4; ++a)
#pragma unroll
        for (int c = 0; c < 2; ++c) acc[a][c] = (f32x4){0.f, 0.f, 0.f, 0.f};
#pragma unroll
    for (int s = 0; s < 2; ++s) {
        f16x8 a[4];
#pragma unroll
        for (int sub = 0; sub < 4; ++sub)
            a[sub] = *(const f16x8*)&Hs[(w * 64 + sub * 16 + m) * 72 + s * 32 + q * 8];
#pragma unroll
        for (int c = 0; c < 2; ++c) {
            f16x8 b = *(const f16x8*)&Ws2[(((c * 2 + s) * 4 + q) * 16 + m) * 8];
#pragma unroll
            for (int sub = 0; sub < 4; ++sub)
                acc[sub][c] = __builtin_amdgcn_mfma_f32_16x16x32_f16(a[sub], b, acc[sub][c], 0, 0, 0);
        }
    }
#pragma unroll
    for (int sub = 0; sub < 4; ++sub)
#pragma unroll
    for (int c = 0; c < 2; ++c)
#pragma unroll
    for (int r = 0; r < 4; ++r) {
        int gn = n0 + w * 64 + sub * 16 + q * 4 + r;
        if (gn < N) {
            int C = c * 16 + m;
            _Float16 v = (_Float16)acc[sub][c][r];
            if (C < 16) xlh[(long)gn * 16 + C] = v;
            else        xrh[(long)gn * 16 + (C - 16)] = v;
        }
    }
}

// ---- Attention layer 1: 16 lanes/node (4 nodes/wave) -------------------
// lane layout: [node_sub 2b][g 1b][q 3b]; q = dim octet, g = edge group.
// Merge across groups = 1 shfl level (vs 3); prologue/epilogue amortized 4x.
__global__ void k_att1(const f16x8* __restrict__ xlh, const f16x8* __restrict__ xrh,
                       const float* __restrict__ a1, const float* __restrict__ b1,
                       const int* __restrict__ rowptr, const int* __restrict__ col,
                       f16x8* __restrict__ hout, int N) {
    int n = (int)((blockIdx.x * (unsigned)blockDim.x + threadIdx.x) >> 4);
    int lane = threadIdx.x & 63;
    if (n >= N) return;
    int q = lane & 7;          // dim octet: dims q*8 .. q*8+7
    int g = (lane >> 3) & 1;   // edge group 0..1
    float4 af0 = ((const float4*)a1)[q * 2 + 0];
    float4 af1 = ((const float4*)a1)[q * 2 + 1];
    half2v a01 = {(_Float16)af0.x, (_Float16)af0.y};
    half2v a23 = {(_Float16)af0.z, (_Float16)af0.w};
    half2v a45 = {(_Float16)af1.x, (_Float16)af1.y};
    half2v a67 = {(_Float16)af1.z, (_Float16)af1.w};
    f16x8 xrv = xrh[(long)n * 8 + q];
    int jb = rowptr[n], je = rowptr[n + 1];
    float l = 0.f;
    float o[8] = {0.f, 0.f, 0.f, 0.f, 0.f, 0.f, 0.f, 0.f};
    int j = jb + g;
    // main: 2 edges per group per iteration (this group's edges are stride-2)
    for (; j + 2 < je; j += 4) {
        int s0 = col[j], s1 = col[j + 2];
        f16x8 xh0 = xlh[(long)s0 * 8 + q];
        f16x8 xh1 = xlh[(long)s1 * 8 + q];
        f16x8 t0 = xh0 + xrv, t1 = xh1 + xrv;
        f16x8 u0 = __builtin_elementwise_max(t0, t0 * (_Float16)0.2f);
        f16x8 u1 = __builtin_elementwise_max(t1, t1 * (_Float16)0.2f);
        half2v u0a = {u0[0], u0[1]}, u0b = {u0[2], u0[3]}, u0c = {u0[4], u0[5]}, u0d = {u0[6], u0[7]};
        half2v u1a = {u1[0], u1[1]}, u1b = {u1[2], u1[3]}, u1c = {u1[4], u1[5]}, u1d = {u1[6], u1[7]};
        float e0 = __builtin_amdgcn_fdot2(u0a, a01,
                    __builtin_amdgcn_fdot2(u0b, a23,
                     __builtin_amdgcn_fdot2(u0c, a45,
                      __builtin_amdgcn_fdot2(u0d, a67, 0.f, false), false), false), false);
        float e1 = __builtin_amdgcn_fdot2(u1a, a01,
                    __builtin_amdgcn_fdot2(u1b, a23,
                     __builtin_amdgcn_fdot2(u1c, a45,
                      __builtin_amdgcn_fdot2(u1d, a67, 0.f, false), false), false), false);
#pragma unroll
        for (int off = 1; off < 8; off <<= 1) {
            e0 += __shfl_xor(e0, off, 8);
            e1 += __shfl_xor(e1, off, 8);
        }
        float c0 = __expf(e0), c1 = __expf(e1);
        l += c0 + c1;
#pragma unroll
        for (int i = 0; i < 8; ++i)
            o[i] = fmaf(c0, (float)xh0[i], fmaf(c1, (float)xh1[i], o[i]));
    }
    // tail: at most one edge per group
    for (; j < je; j += 2) {
        int s = col[j];
        f16x8 xh = xlh[(long)s * 8 + q];
        f16x8 t = xh + xrv;
        f16x8 u = __builtin_elementwise_max(t, t * (_Float16)0.2f);
        half2v ua = {u[0], u[1]}, ub = {u[2], u[3]}, uc = {u[4], u[5]}, ud = {u[6], u[7]};
        float e = __builtin_amdgcn_fdot2(ua, a01,
                   __builtin_amdgcn_fdot2(ub, a23,
                    __builtin_amdgcn_fdot2(uc, a45,
                     __builtin_amdgcn_fdot2(ud, a67, 0.f, false), false), false), false);
#pragma unroll
        for (int off = 1; off < 8; off <<= 1) e += __shfl_xor(e, off, 8);
        float c = __expf(e);
        l += c;
#pragma unroll
        for (int i = 0; i < 8; ++i) o[i] = fmaf(c, (float)xh[i], o[i]);
    }
    // merge the 2 edge groups (lane bit 3)
    l += __shfl_xor(l, 8);
#pragma unroll
    for (int i = 0; i < 8; ++i) o[i] += __shfl_xor(o[i], 8);
    if (g == 0) {
        float4 bv0 = ((const float4*)b1)[q * 2 + 0];
        float4 bv1 = ((const float4*)b1)[q * 2 + 1];
        float bb[8] = {bv0.x, bv0.y, bv0.z, bv0.w, bv1.x, bv1.y, bv1.z, bv1.w};
        float rl = 1.f / l;
        f16x8 hv;
#pragma unroll
        for (int i = 0; i < 8; ++i) {
            float h = o[i] * rl + bb[i];
            h = (h > 0.f) ? h : (__expf(h) - 1.f);
            hv[i] = (_Float16)h;
        }
        hout[(long)n * 8 + q] = hv;
    }
}

// ---- Attention layer 2 + softmax: 16 lanes/node (4 nodes/wave) ---------
// lane layout: [node_sub 2b][g 2b][q 2b]; q = dim quad, g = edge group 0..3.
__global__ void k_att2(const half4* __restrict__ xlh, const half4* __restrict__ xrh,
                       const float* __restrict__ a2, const float* __restrict__ b2v,
                       const int* __restrict__ rowptr, const int* __restrict__ col,
                       float* __restrict__ out, int N) {
    int n = (int)((blockIdx.x * (unsigned)blockDim.x + threadIdx.x) >> 4);
    int lane = threadIdx.x & 63;
    if (n >= N) return;
    int q = lane & 3;
    int g = (lane >> 2) & 3;
    float4 af = ((const float4*)a2)[q];
    half2v alo = {(_Float16)af.x, (_Float16)af.y};
    half2v ahi = {(_Float16)af.z, (_Float16)af.w};
    half4 xrv = xrh[(long)n * 4 + q];
    int jb = rowptr[n], je = rowptr[n + 1];
    float l = 0.f;
    float4 o = {0.f, 0.f, 0.f, 0.f};
    int j = jb + g;
    // main: 2 edges per group per iteration (group's edges are stride-4)
    for (; j + 4 < je; j += 8) {
        int s0 = col[j], s1 = col[j + 4];
        half4 xh0 = xlh[(long)s0 * 4 + q];
        half4 xh1 = xlh[(long)s1 * 4 + q];
        half4 t0 = xh0 + xrv, t1 = xh1 + xrv;
        half4 u0 = __builtin_elementwise_max(t0, t0 * (_Float16)0.2f);
        half4 u1 = __builtin_elementwise_max(t1, t1 * (_Float16)0.2f);
        half2v u0lo = {u0.x, u0.y}, u0hi = {u0.z, u0.w};
        half2v u1lo = {u1.x, u1.y}, u1hi = {u1.z, u1.w};
        float e0 = __builtin_amdgcn_fdot2(u0lo, alo,
                    __builtin_amdgcn_fdot2(u0hi, ahi, 0.f, false), false);
        float e1 = __builtin_amdgcn_fdot2(u1lo, alo,
                    __builtin_amdgcn_fdot2(u1hi, ahi, 0.f, false), false);
        e0 += __shfl_xor(e0, 1, 4); e0 += __shfl_xor(e0, 2, 4);
        e1 += __shfl_xor(e1, 1, 4); e1 += __shfl_xor(e1, 2, 4);
        float c0 = __expf(e0), c1 = __expf(e1);
        l += c0 + c1;
        o.x = fmaf(c0, (float)xh0.x, fmaf(c1, (float)xh1.x, o.x));
        o.y = fmaf(c0, (float)xh0.y, fmaf(c1, (float)xh1.y, o.y));
        o.z = fmaf(c0, (float)xh0.z, fmaf(c1, (float)xh1.z, o.z));
        o.w = fmaf(c0, (float)xh0.w, fmaf(c1, (float)xh1.w, o.w));
    }
    for (; j < je; j += 4) {
        int s = col[j];
        half4 xh = xlh[(long)s * 4 + q];
        half4 t = xh + xrv;
        half4 u = __builtin_elementwise_max(t, t * (_Float16)0.2f);
        half2v ulo = {u.x, u.y}, uhi = {u.z, u.w};
        float e = __builtin_amdgcn_fdot2(ulo, alo,
                   __builtin_amdgcn_fdot2(uhi, ahi, 0.f, false), false);
        e += __shfl_xor(e, 1, 4);
        e += __shfl_xor(e, 2, 4);
        float c = __expf(e);
        l += c;
        o.x = fmaf(c, (float)xh.x, o.x);
        o.y = fmaf(c, (float)xh.y, o.y);
        o.z = fmaf(c, (float)xh.z, o.z);
        o.w = fmaf(c, (float)xh.w, o.w);
    }
    // merge the 4 edge groups (lane bits 2,3)
#pragma unroll
    for (int off = 4; off <= 8; off <<= 1) {
        l   += __shfl_xor(l, off);
        o.x += __shfl_xor(o.x, off);
        o.y += __shfl_xor(o.y, off);
        o.z += __shfl_xor(o.z, off);
        o.w += __shfl_xor(o.w, off);
    }
    if (g == 0) {
        float4 bv = ((const float4*)b2v)[q];
        float rl = 1.f / l;
        float4 z;
        z.x = o.x * rl + bv.x;
        z.y = o.y * rl + bv.y;
        z.z = o.z * rl + bv.z;
        z.w = o.w * rl + bv.w;
        float mx = fmaxf(fmaxf(z.x, z.y), fmaxf(z.z, z.w));
        mx = fmaxf(mx, __shfl_xor(mx, 1, 4));
        mx = fmaxf(mx, __shfl_xor(mx, 2, 4));
        float4 ez;
        ez.x = __expf(z.x - mx); ez.y = __expf(z.y - mx);
        ez.z = __expf(z.z - mx); ez.w = __expf(z.w - mx);
        float ss = ez.x + ez.y + ez.z + ez.w;
        ss += __shfl_xor(ss, 1, 4);
        ss += __shfl_xor(ss, 2, 4);
        float rs = 1.f / ss;
        ez.x *= rs; ez.y *= rs; ez.z *= rs; ez.w *= rs;
        ((float4*)out)[(long)n * 4 + q] = ez;
    }
}

// ---- launch ------------------------------------------------------------
extern "C" void kernel_launch(void* const* d_in, const int* in_sizes, int n_in,
                              void* d_out, int out_size, void* d_ws, size_t ws_size,
                              hipStream_t stream) {
    const float* X   = (const float*)d_in[0];
    const int*   ei  = (const int*)d_in[1];
    const float* W1l = (const float*)d_in[3];
    const float* W1r = (const float*)d_in[4];
    const float* a1  = (const float*)d_in[5];
    const float* b1  = (const float*)d_in[6];
    const float* W2l = (const float*)d_in[7];
    const float* W2r = (const float*)d_in[8];
    const float* a2  = (const float*)d_in[9];
    const float* b2  = (const float*)d_in[10];

    int N = in_sizes[0] / F_DIM;
    int E = in_sizes[1] / 2;
    int M = E + N;
    int NBUK = (N + 255) >> BUK_SH;
    int NH = NBUK * NCH;
    int CH = (E + NCH - 1) / NCH;
    const int* srcv = ei;
    const int* dstv = ei + E;

    char* w = (char*)d_ws;
    size_t off = 0;
    auto alloc = [&](size_t bytes) -> char* {
        char* p = w + off;
        off = (off + bytes + 255) & ~(size_t)255;
        return p;
    };
    int* rowptr  = (int*)alloc((size_t)(N + 1) * sizeof(int));
    int* hist    = (int*)alloc((size_t)NH * sizeof(int));
    int* bktTot  = (int*)alloc((size_t)NBUK * sizeof(int));
    int* bktBase = (int*)alloc((size_t)(NBUK + 1) * sizeof(int));
    int* col     = (int*)alloc((size_t)M * sizeof(int));
    uint32_t* binned = (uint32_t*)alloc((size_t)E * sizeof(uint32_t));
    _Float16* xl1h = (_Float16*)alloc((size_t)N * H_DIM * 2);
    _Float16* xr1h = (_Float16*)alloc((size_t)N * H_DIM * 2);
    _Float16* h1h  = (_Float16*)alloc((size_t)N * H_DIM * 2);
    _Float16* xl2h = (_Float16*)alloc((size_t)N * K_DIM * 2);
    _Float16* xr2h = (_Float16*)alloc((size_t)N * K_DIM * 2);

    // CSR build (5 launches)
    k_hist<<<NCH, 256, 0, stream>>>(dstv, hist, E, CH, NBUK);
    k_scanBkt<<<NBUK, 256, 0, stream>>>(hist, bktTot);
    k_scanTot<<<1, 256, 0, stream>>>(bktTot, bktBase, NBUK);
    k_scatter<<<NCH, 256, 0, stream>>>(srcv, dstv, hist, bktBase, binned, E, CH, NBUK);
    k_fine2<<<NBUK, 256, 0, stream>>>(binned, bktBase, rowptr, col, N);

    // layers (4 launches)
    int g1Blocks = (N + 127) / 128;
    k_gemm1m<<<g1Blocks, 256, 0, stream>>>(X, W1l, W1r, xl1h, xr1h, N);
    int nodeBlocks16 = (N + 15) / 16;   // 16 nodes per 256-thread block
    k_att1<<<nodeBlocks16, 256, 0, stream>>>((const f16x8*)xl1h, (const f16x8*)xr1h,
                                             a1, b1, rowptr, col, (f16x8*)h1h, N);
    int g2Blocks = (N + 255) / 256;
    k_gemm2m<<<g2Blocks, 256, 0, stream>>>(h1h, W2l, W2r, xl2h, xr2h, N);
    k_att2<<<nodeBlocks16, 256, 0, stream>>>((const half4*)xl2h, (const half4*)xr2h,
                                             a2, b2, rowptr, col, (float*)d_out, N);
}